// Round 2
// baseline (2122.115 us; speedup 1.0000x reference)
//
#include <hip/hip_runtime.h>

// TruncatedHistoryAttn, round 8.
// Phase 1 (unchanged): fp32 tiled GEMM  A = H@W1 (-> ws), B2 = H@W2 (-> d_out).
// Phase 2: latency-optimized sync.
//  - Tagged 8-byte words (float partial | step tag): the atomic store IS the
//    publication. No vmcnt drain, no flag store, no flag-then-data double
//    round trip. 2-slot parity buffer; a slot is only overwritten after all
//    WGs published the following step (=> their reads completed).
//  - All 8 waves poll the 40 words and do combine+softmax locally: no
//    weights-broadcast barrier.
//  - Matvec reads tilde via __shfl of the wave's own lanes (wave q's
//    k-segment == its own lanes' tld): no tlds LDS buffer, no barrier.
//  - One barrier/step (pm k-segment reduce). W3 in plain VGPRs.
//  - Output row t written at step t (poll of tag t+1 proves every wave-0
//    consumed B2 row t into registers).

#define BB 32
#define SS 512
#define DD 512
#define NS 5
#define KWG 8

#define A_ELEMS    ((size_t)BB * SS * DD)            // 32 MB
#define EXCH_U64_PER_B 128                           // 2 slots x 64 (40 used)
#define EXCH_OFF   (A_ELEMS * 4)
#define EXCH_BYTES ((size_t)BB * EXCH_U64_PER_B * 8) // 32 KB
#define WS_NEED    (EXCH_OFF + EXCH_BYTES)

typedef __attribute__((ext_vector_type(4))) float f32x4;

// ---------------- Phase 1: A = H@W1, B2 = H@W2 (fp32) ----------------
__global__ void __launch_bounds__(256) th_phase1(
    const float* __restrict__ H, const float* __restrict__ W1,
    const float* __restrict__ W2, float* __restrict__ A, float* __restrict__ B2) {
  const int tid = threadIdx.x;
  const int mt = blockIdx.x >> 3;
  const int nt = blockIdx.x & 7;
  const int m0 = mt << 6, n0 = nt << 6;
  __shared__ float Ht[64][20];
  __shared__ float Wt1[16][64];
  __shared__ float Wt2[16][64];
  const int tx = tid & 15, ty = tid >> 4;
  const int sr = tid >> 2, sk = (tid & 3) << 2;
  const int wr = tid >> 4, wn = (tid & 15) << 2;
  float a1[4][4] = {{0.f}}, a2[4][4] = {{0.f}};

  for (int k0 = 0; k0 < DD; k0 += 16) {
    float4 hv  = *(const float4*)&H[(size_t)(m0 + sr) * DD + k0 + sk];
    float4 w1v = *(const float4*)&W1[(size_t)(k0 + wr) * DD + n0 + wn];
    float4 w2v = *(const float4*)&W2[(size_t)(k0 + wr) * DD + n0 + wn];
    *(float4*)&Ht[sr][sk]  = hv;
    *(float4*)&Wt1[wr][wn] = w1v;
    *(float4*)&Wt2[wr][wn] = w2v;
    __syncthreads();
#pragma unroll
    for (int kq = 0; kq < 16; kq += 4) {
      float hs[4][4];
#pragma unroll
      for (int i = 0; i < 4; ++i) {
        float4 h4 = *(const float4*)&Ht[ty * 4 + i][kq];
        hs[i][0] = h4.x; hs[i][1] = h4.y; hs[i][2] = h4.z; hs[i][3] = h4.w;
      }
#pragma unroll
      for (int kk = 0; kk < 4; ++kk) {
        float4 w1f = *(const float4*)&Wt1[kq + kk][tx * 4];
        float4 w2f = *(const float4*)&Wt2[kq + kk][tx * 4];
#pragma unroll
        for (int i = 0; i < 4; ++i) {
          float h = hs[i][kk];
          a1[i][0] = fmaf(h, w1f.x, a1[i][0]);
          a1[i][1] = fmaf(h, w1f.y, a1[i][1]);
          a1[i][2] = fmaf(h, w1f.z, a1[i][2]);
          a1[i][3] = fmaf(h, w1f.w, a1[i][3]);
          a2[i][0] = fmaf(h, w2f.x, a2[i][0]);
          a2[i][1] = fmaf(h, w2f.y, a2[i][1]);
          a2[i][2] = fmaf(h, w2f.z, a2[i][2]);
          a2[i][3] = fmaf(h, w2f.w, a2[i][3]);
        }
      }
    }
    __syncthreads();
  }
#pragma unroll
  for (int i = 0; i < 4; ++i) {
    float4 o1 = make_float4(a1[i][0], a1[i][1], a1[i][2], a1[i][3]);
    float4 o2 = make_float4(a2[i][0], a2[i][1], a2[i][2], a2[i][3]);
    size_t off = (size_t)(m0 + ty * 4 + i) * DD + n0 + tx * 4;
    *(float4*)&A[off]  = o1;
    *(float4*)&B2[off] = o2;
  }
}

// ---------------- Phase 2: the recurrence ----------------
// grid 256 = 8 WGs/batch; bid = g*32+b -> all siblings on one XCD (mod-8 rr).
__global__ void __launch_bounds__(512) th_phase2(
    const float* __restrict__ H, const float* __restrict__ v,
    const float* __restrict__ W3, const float* __restrict__ A,
    float* __restrict__ Ob,  // d_out: holds B2, overwritten with tilde rows
    unsigned long long* __restrict__ exch) {
  const int tid = threadIdx.x;
  const int b = blockIdx.x & 31;
  const int g = blockIdx.x >> 5;     // 0..7: cols [g*64, g*64+64)
  const int q = tid >> 6;            // wave id == k-segment 0..7 (64 k each)
  const int ln = tid & 63;
  const int col = (g << 6) + ln;

  __shared__ float pm[DD];           // matvec k-segment partials

  // W3 slice in plain VGPRs: wa[i] = W3[q*64+i][col]
  float wa[64];
#pragma unroll
  for (int i = 0; i < 64; ++i)
    wa[i] = W3[(size_t)(q * 64 + i) * DD + col];

  const float* Hb = H + (size_t)b * SS * DD;
  const float* Ab = A + (size_t)b * SS * DD;
  float* Op = Ob + (size_t)b * SS * DD;
  unsigned long long* eb = exch + (size_t)b * EXCH_U64_PER_B;

  float v_col = 0.f;
  float aA[NS] = {0.f, 0.f, 0.f, 0.f, 0.f};
  float cC[NS] = {0.f, 0.f, 0.f, 0.f, 0.f};
  float tl[NS] = {0.f, 0.f, 0.f, 0.f, 0.f};
  float h_cur = Hb[tid];

  // ---- prologue: scores for step 0 (history all zero -> x = b0, all j equal)
  if (q == 0) {
    v_col = v[col];
    float bt0 = Op[col];
    float e = __expf(2.0f * bt0);
    float s = (1.0f - 2.0f / (e + 1.0f)) * v_col;
#pragma unroll
    for (int off = 32; off >= 1; off >>= 1) s += __shfl_xor(s, off, 64);
    if (ln < NS)
      __hip_atomic_store(&eb[g * 5 + ln],
          (unsigned long long)__float_as_uint(s) | (1ull << 32),
          __ATOMIC_RELAXED, __HIP_MEMORY_SCOPE_AGENT);
  }

  const int lsrc = ((ln & 7) * 5) + (ln >> 3);   // word layout g*5+j -> j*8+g

#pragma unroll 1
  for (int t5 = 0; t5 < 515; t5 += 5) {
#pragma unroll
    for (int p = 0; p < NS; ++p) {
      const int t = t5 + p;
      if (t < SS) {
        const bool pub = (t + 1 < SS);
        // ---- wave-0 prefetch for the end-of-step publish (hidden by step)
        float aN_v = 0.f, bt_v = 0.f;
        if (q == 0 && pub) {
          aN_v = Ab[(size_t)t * DD + col];        // A row t
          bt_v = Op[(size_t)(t + 1) * DD + col];  // B2 row t+1
        }
        float h_nxt = 0.f;
        if (pub) h_nxt = Hb[(size_t)(t + 1) * DD + tid];

        // ---- poll 40 tagged words (slot t&1, tag t+1), all waves
        const unsigned long long* wsl = eb + (size_t)(t & 1) * 64;
        float pv = 0.f;
        if (ln < 40) {
          unsigned long long w;
          do {
            w = __hip_atomic_load(&wsl[ln], __ATOMIC_RELAXED,
                                  __HIP_MEMORY_SCOPE_AGENT);
          } while ((unsigned)(w >> 32) != (unsigned)(t + 1));
          pv = __uint_as_float((unsigned)w);
        }
        // transpose to j*8+g, reduce over g, broadcast 5 totals
        float pt = __shfl(pv, lsrc, 64);
        pt += __shfl_xor(pt, 1, 64);
        pt += __shfl_xor(pt, 2, 64);
        pt += __shfl_xor(pt, 4, 64);
        float sc0 = __shfl(pt, 0, 64);
        float sc1 = __shfl(pt, 8, 64);
        float sc2 = __shfl(pt, 16, 64);
        float sc3 = __shfl(pt, 24, 64);
        float sc4 = __shfl(pt, 32, 64);
        float mx = fmaxf(fmaxf(fmaxf(sc0, sc1), fmaxf(sc2, sc3)), sc4);
        float e0 = __expf(sc0 - mx), e1 = __expf(sc1 - mx);
        float e2 = __expf(sc2 - mx), e3 = __expf(sc3 - mx);
        float e4 = __expf(sc4 - mx);
        float inv = 1.0f / (e0 + e1 + e2 + e3 + e4);

        // ---- tilde (all threads, registers only)
        float hh = (e0 * inv) * tl[p];
        hh = fmaf(e1 * inv, tl[(p + 1) % NS], hh);
        hh = fmaf(e2 * inv, tl[(p + 2) % NS], hh);
        hh = fmaf(e3 * inv, tl[(p + 3) % NS], hh);
        hh = fmaf(e4 * inv, tl[(p + 4) % NS], hh);
        float tld = h_cur + fmaxf(hh, 0.f);
        tl[p] = tld;
        // poll passed => every wave-0 consumed B2 row t => row t is dead
        if (g == 0) Op[(size_t)t * DD + tid] = tld;

        // ---- matvec: wave q's k-segment == its own lanes' tld (shfl)
        float a0 = 0.f, a1 = 0.f, a2 = 0.f, a3 = 0.f;
#pragma unroll
        for (int k = 0; k < 64; k += 4) {
          a0 = fmaf(__shfl(tld, k + 0, 64), wa[k + 0], a0);
          a1 = fmaf(__shfl(tld, k + 1, 64), wa[k + 1], a1);
          a2 = fmaf(__shfl(tld, k + 2, 64), wa[k + 2], a2);
          a3 = fmaf(__shfl(tld, k + 3, 64), wa[k + 3], a3);
        }
        pm[tid] = (a0 + a1) + (a2 + a3);
        __syncthreads();                         // the one barrier per step

        // ---- wave 0: k-reduce, scores for step t+1, tagged publish
        if (q == 0) {
          float c = 0.f;
#pragma unroll
          for (int s = 0; s < 8; ++s) c += pm[s * 64 + ln];
          aA[p] = aN_v;                          // A row t
          cC[p] = c;                             // c row t
          if (pub) {
            float sj[NS];
#pragma unroll
            for (int j = 0; j < NS; ++j) {
              int sl = (p + 1 + j) % NS;         // rows t-4 .. t
              float x = aA[sl] + bt_v + cC[sl];
              float e = __expf(2.0f * x);
              sj[j] = (1.0f - 2.0f / (e + 1.0f)) * v_col;
            }
#pragma unroll
            for (int j = 0; j < NS; ++j) {
#pragma unroll
              for (int off = 32; off >= 1; off >>= 1)
                sj[j] += __shfl_xor(sj[j], off, 64);
            }
            float val = sj[0];
            val = (ln == 1) ? sj[1] : val;
            val = (ln == 2) ? sj[2] : val;
            val = (ln == 3) ? sj[3] : val;
            val = (ln == 4) ? sj[4] : val;
            if (ln < NS)
              __hip_atomic_store(&eb[(size_t)((t + 1) & 1) * 64 + g * 5 + ln],
                  (unsigned long long)__float_as_uint(val) |
                      ((unsigned long long)(t + 2) << 32),
                  __ATOMIC_RELAXED, __HIP_MEMORY_SCOPE_AGENT);
          }
        }
        h_cur = h_nxt;
      }
    }
  }
}

extern "C" void kernel_launch(void* const* d_in, const int* in_sizes, int n_in,
                              void* d_out, int out_size, void* d_ws, size_t ws_size,
                              hipStream_t stream) {
  const float* H  = (const float*)d_in[0];
  const float* v  = (const float*)d_in[1];
  const float* W1 = (const float*)d_in[2];
  const float* W2 = (const float*)d_in[3];
  const float* W3 = (const float*)d_in[4];
  float* out = (float*)d_out;

  if (ws_size < WS_NEED) return;

  float* A = (float*)d_ws;
  unsigned long long* exch = (unsigned long long*)((char*)d_ws + EXCH_OFF);

  (void)hipMemsetAsync(exch, 0, EXCH_BYTES, stream);
  hipLaunchKernelGGL(th_phase1, dim3(256 * 8), dim3(256), 0, stream,
                     H, W1, W2, A, out);
  hipLaunchKernelGGL(th_phase2, dim3(BB * KWG), dim3(512), 0, stream,
                     H, v, W3, A, out, exch);
}

// Round 3
// 1414.248 us; speedup vs baseline: 1.5005x; 1.5005x over previous
//
#include <hip/hip_runtime.h>

// TruncatedHistoryAttn, round 9.
// Phase 1 (unchanged): fp32 tiled GEMM  A = H@W1 (-> ws), B2 = H@W2 (-> d_out).
// Phase 2 = round-7 skeleton + latency cures (round-8 post-mortem: agent-scope
// atomics round-trip the LLC ~700cy/leg; round 7 paid ~3-4 dependent legs):
//  - Tagged 8B words (float partial | step tag): the store IS the publication.
//    No vmcnt drain, no flag store, no flag-then-data double round trip.
//  - Wave 0 ONLY polls (round 8's all-wave polling hammered L3), and only the
//    35 FOREIGN words: its own 5 partials stay in registers post-reduce, so
//    self-publish visibility is off the critical chain.
//  - Word layout j*8+g: combine = 3 shfl_xor (over g) + 5 broadcasts, no
//    transpose shfl.
//  - Barrier-B eliminated: wave q's matvec k-segment [q*64,q*64+64) reads only
//    its OWN lanes' tilde values -> tlds write + s_waitcnt lgkmcnt(0) + b128
//    reads are wave-local (no cross-wave dependency). 2 barriers/step (was 3).
//    Matvec stays ds_read_b128 (round 8's 64x ds_bpermute = 2M bank conflicts).
//  - W3 in plain VGPRs. Step-0 weights are exactly uniform (history=0) -> no
//    prologue exchange; wl init 0.2. Output row t stored at step t (poll of
//    tag t+1 proves all siblings consumed B2 row t).
// Slot safety: publish(t+2 -> slot (t+1)&1) only after our poll of tag t+1
// passed => all siblings completed step t-1 => done reading that slot.

#define BB 32
#define SS 512
#define DD 512
#define NS 5

#define A_ELEMS    ((size_t)BB * SS * DD)            // 32 MB
#define EXCH_U64_PER_B 128                           // 2 slots x 64 (40 used)
#define EXCH_OFF   (A_ELEMS * 4)
#define EXCH_BYTES ((size_t)BB * EXCH_U64_PER_B * 8) // 32 KB
#define WS_NEED    (EXCH_OFF + EXCH_BYTES)

typedef __attribute__((ext_vector_type(4))) float f32x4;

// ---------------- Phase 1: A = H@W1, B2 = H@W2 (fp32) ----------------
__global__ void __launch_bounds__(256) th_phase1(
    const float* __restrict__ H, const float* __restrict__ W1,
    const float* __restrict__ W2, float* __restrict__ A, float* __restrict__ B2) {
  const int tid = threadIdx.x;
  const int mt = blockIdx.x >> 3;
  const int nt = blockIdx.x & 7;
  const int m0 = mt << 6, n0 = nt << 6;
  __shared__ float Ht[64][20];
  __shared__ float Wt1[16][64];
  __shared__ float Wt2[16][64];
  const int tx = tid & 15, ty = tid >> 4;
  const int sr = tid >> 2, sk = (tid & 3) << 2;
  const int wr = tid >> 4, wn = (tid & 15) << 2;
  float a1[4][4] = {{0.f}}, a2[4][4] = {{0.f}};

  for (int k0 = 0; k0 < DD; k0 += 16) {
    float4 hv  = *(const float4*)&H[(size_t)(m0 + sr) * DD + k0 + sk];
    float4 w1v = *(const float4*)&W1[(size_t)(k0 + wr) * DD + n0 + wn];
    float4 w2v = *(const float4*)&W2[(size_t)(k0 + wr) * DD + n0 + wn];
    *(float4*)&Ht[sr][sk]  = hv;
    *(float4*)&Wt1[wr][wn] = w1v;
    *(float4*)&Wt2[wr][wn] = w2v;
    __syncthreads();
#pragma unroll
    for (int kq = 0; kq < 16; kq += 4) {
      float hs[4][4];
#pragma unroll
      for (int i = 0; i < 4; ++i) {
        float4 h4 = *(const float4*)&Ht[ty * 4 + i][kq];
        hs[i][0] = h4.x; hs[i][1] = h4.y; hs[i][2] = h4.z; hs[i][3] = h4.w;
      }
#pragma unroll
      for (int kk = 0; kk < 4; ++kk) {
        float4 w1f = *(const float4*)&Wt1[kq + kk][tx * 4];
        float4 w2f = *(const float4*)&Wt2[kq + kk][tx * 4];
#pragma unroll
        for (int i = 0; i < 4; ++i) {
          float h = hs[i][kk];
          a1[i][0] = fmaf(h, w1f.x, a1[i][0]);
          a1[i][1] = fmaf(h, w1f.y, a1[i][1]);
          a1[i][2] = fmaf(h, w1f.z, a1[i][2]);
          a1[i][3] = fmaf(h, w1f.w, a1[i][3]);
          a2[i][0] = fmaf(h, w2f.x, a2[i][0]);
          a2[i][1] = fmaf(h, w2f.y, a2[i][1]);
          a2[i][2] = fmaf(h, w2f.z, a2[i][2]);
          a2[i][3] = fmaf(h, w2f.w, a2[i][3]);
        }
      }
    }
    __syncthreads();
  }
#pragma unroll
  for (int i = 0; i < 4; ++i) {
    float4 o1 = make_float4(a1[i][0], a1[i][1], a1[i][2], a1[i][3]);
    float4 o2 = make_float4(a2[i][0], a2[i][1], a2[i][2], a2[i][3]);
    size_t off = (size_t)(m0 + ty * 4 + i) * DD + n0 + tx * 4;
    *(float4*)&A[off]  = o1;
    *(float4*)&B2[off] = o2;
  }
}

// ---------------- Phase 2: the recurrence ----------------
// grid 256 = 8 WGs/batch; bid = g*32+b -> all siblings on one XCD (mod-8 rr).
__global__ void __launch_bounds__(512) th_phase2(
    const float* __restrict__ H, const float* __restrict__ v,
    const float* __restrict__ W3, const float* __restrict__ A,
    float* __restrict__ Ob,  // d_out: holds B2, overwritten with tilde rows
    unsigned long long* __restrict__ exch) {
  const int tid = threadIdx.x;
  const int b = blockIdx.x & 31;
  const int g = blockIdx.x >> 5;     // 0..7: cols [g*64, g*64+64)
  const int q = tid >> 6;            // wave id == k-segment 0..7 (64 k each)
  const int ln = tid & 63;
  const int col = (g << 6) + ln;

  __shared__ float tlds[DD];         // tilde_t row
  __shared__ float pm[DD];           // matvec k-segment partials
  __shared__ float wl[8];            // softmax weights broadcast

  // W3 slice in plain VGPRs: wa[i] = W3[q*64+i][col]
  float wa[64];
#pragma unroll
  for (int i = 0; i < 64; ++i)
    wa[i] = W3[(size_t)(q * 64 + i) * DD + col];

  const float* Hb = H + (size_t)b * SS * DD;
  const float* Ab = A + (size_t)b * SS * DD;
  float* Op = Ob + (size_t)b * SS * DD;
  unsigned long long* eb = exch + (size_t)b * EXCH_U64_PER_B;

  float v_col = (q == 0) ? v[col] : 0.f;
  float aA[NS] = {0.f, 0.f, 0.f, 0.f, 0.f};
  float cC[NS] = {0.f, 0.f, 0.f, 0.f, 0.f};
  float tl[NS] = {0.f, 0.f, 0.f, 0.f, 0.f};
  // own published partials (persist across the step boundary; substituted
  // into the poll so self-publish visibility is off the chain)
  float s0 = 0.f, s1 = 0.f, s2 = 0.f, s3 = 0.f, s4 = 0.f;
  float h_cur = Hb[tid];

  if (tid < NS) wl[tid] = 0.2f;      // step-0 weights: exactly uniform
  const int jj = ln >> 3, gg = ln & 7;  // poll word coords (layout j*8+g)

#pragma unroll 1
  for (int t5 = 0; t5 < 515; t5 += 5) {
#pragma unroll
    for (int p = 0; p < NS; ++p) {
      const int t = t5 + p;
      if (t < SS) {
        const bool pub = (t + 1 < SS);
        // ---- prefetches (issued before the poll; consumed post-C / next it.)
        float aN_v = 0.f, bt_v = 0.f;
        if (q == 0 && pub) {
          aN_v = Ab[(size_t)t * DD + col];        // A row t
          bt_v = Op[(size_t)(t + 1) * DD + col];  // B2 row t+1
        }
        float h_nxt = 0.f;
        if (pub) h_nxt = Hb[(size_t)(t + 1) * DD + tid];

        // ---- wave 0: poll foreign 35 tagged words, combine, softmax -> wl
        if (q == 0 && t >= 1) {
          const unsigned long long* wsl = eb + (size_t)(t & 1) * 64;
          float pv = 0.f;
          if (ln < 40) {
            if (gg != g) {
              unsigned long long w;
              do {
                w = __hip_atomic_load(&wsl[ln], __ATOMIC_RELAXED,
                                      __HIP_MEMORY_SCOPE_AGENT);
              } while ((unsigned)(w >> 32) != (unsigned)(t + 1));
              pv = __uint_as_float((unsigned)w);
            } else {
              pv = (jj == 0) ? s0 : (jj == 1) ? s1 : (jj == 2) ? s2
                 : (jj == 3) ? s3 : s4;
            }
          }
          pv += __shfl_xor(pv, 1, 64);
          pv += __shfl_xor(pv, 2, 64);
          pv += __shfl_xor(pv, 4, 64);   // each 8-group holds its j-total
          float sc0 = __shfl(pv, 0, 64);
          float sc1 = __shfl(pv, 8, 64);
          float sc2 = __shfl(pv, 16, 64);
          float sc3 = __shfl(pv, 24, 64);
          float sc4 = __shfl(pv, 32, 64);
          float mx = fmaxf(fmaxf(fmaxf(sc0, sc1), fmaxf(sc2, sc3)), sc4);
          float e0 = __expf(sc0 - mx), e1 = __expf(sc1 - mx);
          float e2 = __expf(sc2 - mx), e3 = __expf(sc3 - mx);
          float e4 = __expf(sc4 - mx);
          float inv = 1.0f / (e0 + e1 + e2 + e3 + e4);
          float wv = e0 * inv;
          wv = (ln == 1) ? e1 * inv : wv;
          wv = (ln == 2) ? e2 * inv : wv;
          wv = (ln == 3) ? e3 * inv : wv;
          wv = (ln == 4) ? e4 * inv : wv;
          if (ln < NS) wl[ln] = wv;
        }
        __syncthreads();                           // A: weights ready

        // ---- all threads: tilde row (registers + 5 broadcast LDS reads)
        float w0 = wl[0], w1 = wl[1], w2 = wl[2], w3_ = wl[3], w4 = wl[4];
        float hh = w0 * tl[p];
        hh = fmaf(w1, tl[(p + 1) % NS], hh);
        hh = fmaf(w2, tl[(p + 2) % NS], hh);
        hh = fmaf(w3_, tl[(p + 3) % NS], hh);
        hh = fmaf(w4, tl[(p + 4) % NS], hh);
        float tld = h_cur + fmaxf(hh, 0.f);
        tl[p] = tld;
        tlds[tid] = tld;
        if (g == 0) Op[(size_t)t * DD + tid] = tld;  // row t dead (poll passed)
        // wave-local: matvec reads ONLY this wave's own tlds segment
        asm volatile("s_waitcnt lgkmcnt(0)" ::: "memory");

        // ---- matvec: own 64 cols, k in [q*64, q*64+64), wave-uniform reads
        float a0 = 0.f, a1 = 0.f, a2 = 0.f, a3 = 0.f;
        const f32x4* tv = (const f32x4*)&tlds[q << 6];
#pragma unroll
        for (int i = 0; i < 16; ++i) {
          f32x4 t4 = tv[i];
          a0 = fmaf(t4.x, wa[4 * i + 0], a0);
          a1 = fmaf(t4.y, wa[4 * i + 1], a1);
          a2 = fmaf(t4.z, wa[4 * i + 2], a2);
          a3 = fmaf(t4.w, wa[4 * i + 3], a3);
        }
        pm[tid] = (a0 + a1) + (a2 + a3);
        __syncthreads();                           // C: pm ready

        // ---- wave 0: k-reduce, scores for step t+1, tagged publish
        if (q == 0) {
          float c = 0.f;
#pragma unroll
          for (int s = 0; s < 8; ++s) c += pm[s * 64 + ln];
          aA[p] = aN_v;                            // A row t -> slot t%5
          cC[p] = c;                               // c row t -> slot t%5
          if (pub) {
            // rows t-4..t live in slots (p+1+j)%5, j = 0..4
            { float x = aA[(p + 1) % NS] + bt_v + cC[(p + 1) % NS];
              float e = __expf(2.f * x); s0 = (1.f - 2.f / (e + 1.f)) * v_col; }
            { float x = aA[(p + 2) % NS] + bt_v + cC[(p + 2) % NS];
              float e = __expf(2.f * x); s1 = (1.f - 2.f / (e + 1.f)) * v_col; }
            { float x = aA[(p + 3) % NS] + bt_v + cC[(p + 3) % NS];
              float e = __expf(2.f * x); s2 = (1.f - 2.f / (e + 1.f)) * v_col; }
            { float x = aA[(p + 4) % NS] + bt_v + cC[(p + 4) % NS];
              float e = __expf(2.f * x); s3 = (1.f - 2.f / (e + 1.f)) * v_col; }
            { float x = aA[p] + bt_v + cC[p];
              float e = __expf(2.f * x); s4 = (1.f - 2.f / (e + 1.f)) * v_col; }
#pragma unroll
            for (int off = 32; off >= 1; off >>= 1) {
              s0 += __shfl_xor(s0, off, 64);
              s1 += __shfl_xor(s1, off, 64);
              s2 += __shfl_xor(s2, off, 64);
              s3 += __shfl_xor(s3, off, 64);
              s4 += __shfl_xor(s4, off, 64);
            }
            float val = s0;
            val = (ln == 1) ? s1 : val;
            val = (ln == 2) ? s2 : val;
            val = (ln == 3) ? s3 : val;
            val = (ln == 4) ? s4 : val;
            if (ln < NS)
              __hip_atomic_store(&eb[(size_t)((t + 1) & 1) * 64 + ln * 8 + g],
                  (unsigned long long)__float_as_uint(val) |
                      ((unsigned long long)(t + 2) << 32),
                  __ATOMIC_RELAXED, __HIP_MEMORY_SCOPE_AGENT);
          }
        }
        h_cur = h_nxt;
      }
    }
  }
}

extern "C" void kernel_launch(void* const* d_in, const int* in_sizes, int n_in,
                              void* d_out, int out_size, void* d_ws, size_t ws_size,
                              hipStream_t stream) {
  const float* H  = (const float*)d_in[0];
  const float* v  = (const float*)d_in[1];
  const float* W1 = (const float*)d_in[2];
  const float* W2 = (const float*)d_in[3];
  const float* W3 = (const float*)d_in[4];
  float* out = (float*)d_out;

  if (ws_size < WS_NEED) return;

  float* A = (float*)d_ws;
  unsigned long long* exch = (unsigned long long*)((char*)d_ws + EXCH_OFF);

  (void)hipMemsetAsync(exch, 0, EXCH_BYTES, stream);
  hipLaunchKernelGGL(th_phase1, dim3(256 * 8), dim3(256), 0, stream,
                     H, W1, W2, A, out);
  hipLaunchKernelGGL(th_phase2, dim3(BB * 8), dim3(512), 0, stream,
                     H, v, W3, A, out, exch);
}